// Round 3
// baseline (91.894 us; speedup 1.0000x reference)
//
#include <hip/hip_runtime.h>
#include <hip/hip_bf16.h>
#include <stdint.h>

typedef __attribute__((ext_vector_type(8))) short short8;
typedef __attribute__((ext_vector_type(4))) float f32x4;
typedef __attribute__((ext_vector_type(4))) unsigned short ushort4v;

#define C_IN 256
#define C_HID 512
#define NHALF_ROWS 4096

// ---------------- threefry-2x32 (matches jax.random) ----------------
__host__ __device__ __forceinline__ void tf2x32(uint32_t k0, uint32_t k1,
                                                uint32_t x0, uint32_t x1,
                                                uint32_t& o0, uint32_t& o1) {
  uint32_t ks2 = k0 ^ k1 ^ 0x1BD11BDAu;
#define TF_RND(r) { x0 += x1; x1 = (x1 << (r)) | (x1 >> (32 - (r))); x1 ^= x0; }
  x0 += k0; x1 += k1;
  TF_RND(13) TF_RND(15) TF_RND(26) TF_RND(6)
  x0 += k1; x1 += ks2 + 1u;
  TF_RND(17) TF_RND(29) TF_RND(16) TF_RND(24)
  x0 += ks2; x1 += k0 + 2u;
  TF_RND(13) TF_RND(15) TF_RND(26) TF_RND(6)
  x0 += k0; x1 += k1 + 3u;
  TF_RND(17) TF_RND(29) TF_RND(16) TF_RND(24)
  x0 += k1; x1 += ks2 + 4u;
  TF_RND(13) TF_RND(15) TF_RND(26) TF_RND(6)
  x0 += ks2; x1 += k0 + 5u;
#undef TF_RND
  o0 = x0; o1 = x1;
}

// bits -> N(0,1) exactly like jax.random.normal (uniform(-1+eps,1) -> sqrt2*erfinv)
__device__ __forceinline__ float bits_to_normal(uint32_t bits) {
  float u = __uint_as_float((bits >> 9) | 0x3f800000u) - 1.0f;  // [0,1)
  const float lo = -0.99999994f;                                 // nextafter(-1,0)
  float v = fmaxf(lo, fmaf(u, 2.0f, lo));                        // (hi-lo)==2.0f in fp32
  float w = -log1pf(-v * v);
  float p;
  if (w < 5.0f) {
    w -= 2.5f;
    p = 2.81022636e-08f;
    p = fmaf(p, w, 3.43273939e-07f);
    p = fmaf(p, w, -3.5233877e-06f);
    p = fmaf(p, w, -4.39150654e-06f);
    p = fmaf(p, w, 0.00021858087f);
    p = fmaf(p, w, -0.00125372503f);
    p = fmaf(p, w, -0.00417768164f);
    p = fmaf(p, w, 0.246640727f);
    p = fmaf(p, w, 1.50140941f);
  } else {
    w = sqrtf(w) - 3.0f;
    p = -0.000200214257f;
    p = fmaf(p, w, 0.000100950558f);
    p = fmaf(p, w, 0.00134934322f);
    p = fmaf(p, w, -0.00367342844f);
    p = fmaf(p, w, 0.00573950773f);
    p = fmaf(p, w, -0.0076224613f);
    p = fmaf(p, w, 0.00943887047f);
    p = fmaf(p, w, 1.00167406f);
    p = fmaf(p, w, 2.83297682f);
  }
  return 1.41421356237f * (p * v);
}

__device__ __forceinline__ unsigned short f2bf16(float f) {  // RNE, finite inputs
  uint32_t u = __float_as_uint(f);
  return (unsigned short)((u + 0x7fffu + ((u >> 16) & 1u)) >> 16);
}

// -------- prep: W1[256][512], W2[512][256] fp32 -> bf16 MFMA B-fragment layout --------
// frag(nt,kt): lane l, elem j holds W[k = kt*32 + (l>>4)*8 + j][n = nt*16 + (l&15)]
__global__ void __launch_bounds__(256) prep_kernel(const float* __restrict__ W1,
                                                   const float* __restrict__ W2,
                                                   short8* __restrict__ W1f,
                                                   short8* __restrict__ W2f) {
  const int t = threadIdx.x;
  const int l = t & 63;
  const int wv = t >> 6;           // 0..3
  const int lr = l & 15;
  const int lkb = (l >> 4) * 8;
  const int b = blockIdx.x;
  short8 v;
  if (b < 64) {                    // W1: 32 n-tiles x 8 k-tiles = 256 frags
    const int f = b * 4 + wv;
    const int nt = f >> 3, kt = f & 7;
    const int n = nt * 16 + lr;
    const int kb = kt * 32 + lkb;
#pragma unroll
    for (int j = 0; j < 8; ++j) v[j] = (short)f2bf16(W1[(kb + j) * 512 + n]);
    W1f[f * 64 + l] = v;
  } else {                         // W2: 16 n-tiles x 16 k-tiles = 256 frags
    const int f = (b - 64) * 4 + wv;
    const int nt = f >> 4, kt = f & 15;
    const int n = nt * 16 + lr;
    const int kb = kt * 32 + lkb;
#pragma unroll
    for (int j = 0; j < 8; ++j) v[j] = (short)f2bf16(W2[(kb + j) * 256 + n]);
    W2f[f * 64 + l] = v;
  }
}

// -------- fused: noise + x -> bf16 LDS -> GEMM1(relu,+b1) -> LDS -> GEMM2(+b2) -> out --------
// block handles 16 "low" rows (b*16..) and 16 "high" rows (+4096) which share threefry calls.
__global__ void __launch_bounds__(512) fused_kernel(
    const float* __restrict__ x, const float* __restrict__ ns,
    const float* __restrict__ b1, const float* __restrict__ b2,
    const short8* __restrict__ W1f, const short8* __restrict__ W2f,
    float* __restrict__ out, uint32_t fk0, uint32_t fk1, int nstep, uint32_t nhalf) {
  __shared__ __align__(16) unsigned char sA[32 * 512];    // 32 rows x 256 bf16 (swizzled)
  __shared__ __align__(16) unsigned char sH[32 * 1024];   // 32 rows x 512 bf16 (swizzled)

  const int t = threadIdx.x;
  const int b = blockIdx.x;
  const float nsv = ns[nstep];

  // ---- stage noisy A tile ----
  {
    const int rl = t >> 5;          // 0..15
    const int ln = t & 31;
    const int r_lo = b * 16 + rl;
    const int r_hi = r_lo + NHALF_ROWS;
    const int sw = (rl & 7) << 4;
#pragma unroll
    for (int i = 0; i < 2; ++i) {
      const int c = (i * 32 + ln) * 4;              // col, multiple of 4
      const float4 xl = *(const float4*)(x + r_lo * C_IN + c);
      const float4 xh = *(const float4*)(x + r_hi * C_IN + c);
      ushort4v vl, vh;
#pragma unroll
      for (int j = 0; j < 4; ++j) {
        uint32_t pidx = (uint32_t)(r_lo * C_IN + c + j);
        uint32_t o0, o1;
        tf2x32(fk0, fk1, pidx, pidx + nhalf, o0, o1);
        float nl = bits_to_normal(o0) * nsv;
        float nh = bits_to_normal(o1) * nsv;
        vl[j] = (unsigned short)f2bf16((&xl.x)[j] + nl);
        vh[j] = (unsigned short)f2bf16((&xh.x)[j] + nh);
      }
      const int byte_base = c * 2;                  // 8B aligned
      *(ushort4v*)(sA + rl * 512 + (byte_base ^ sw)) = vl;
      *(ushort4v*)(sA + (rl + 16) * 512 + (byte_base ^ sw)) = vh;
    }
  }
  __syncthreads();

  const int w = t >> 6;        // wave 0..7
  const int l = t & 63;
  const int m = w & 1;         // row half (0=low rows tile, 1=high rows tile)
  const int nh4 = w >> 1;      // 0..3 n-quadrant
  const int lr = l & 15;
  const int lk = l >> 4;       // 0..3

  // ---- GEMM1: h[32x512] = relu(A @ W1 + b1) ----
  short8 a[8];
  {
    const int row = m * 16 + lr;
    const unsigned char* base = sA + row * 512;
    const int sw = (row & 7) << 4;
#pragma unroll
    for (int kt = 0; kt < 8; ++kt)
      a[kt] = *(const short8*)(base + ((kt * 64 + lk * 16) ^ sw));
  }
  f32x4 acc[8];
#pragma unroll
  for (int i = 0; i < 8; ++i) acc[i] = (f32x4){0.f, 0.f, 0.f, 0.f};
  {
    const short8* bp = W1f + l;
#pragma unroll
    for (int kt = 0; kt < 8; ++kt) {
#pragma unroll
      for (int n = 0; n < 8; ++n) {
        const int f = (nh4 * 8 + n) * 8 + kt;
        acc[n] = __builtin_amdgcn_mfma_f32_16x16x32_bf16(a[kt], bp[f * 64], acc[n], 0, 0, 0);
      }
    }
  }
#pragma unroll
  for (int n = 0; n < 8; ++n) {
    const int col = (nh4 * 8 + n) * 16 + lr;
    const float b1v = b1[col];
#pragma unroll
    for (int j = 0; j < 4; ++j) {
      const int row = m * 16 + lk * 4 + j;
      float v = fmaxf(acc[n][j] + b1v, 0.f);
      *(unsigned short*)(sH + row * 1024 + ((col * 2) ^ ((row & 7) << 4))) = f2bf16(v);
    }
  }
  __syncthreads();

  // ---- GEMM2: y[32x256] = h @ W2 + b2 ----
  short8 ha[16];
  {
    const int row = m * 16 + lr;
    const unsigned char* base = sH + row * 1024;
    const int sw = (row & 7) << 4;
#pragma unroll
    for (int kt = 0; kt < 16; ++kt)
      ha[kt] = *(const short8*)(base + ((kt * 64 + lk * 16) ^ sw));
  }
  f32x4 acc2[4];
#pragma unroll
  for (int i = 0; i < 4; ++i) acc2[i] = (f32x4){0.f, 0.f, 0.f, 0.f};
  {
    const short8* bp = W2f + l;
#pragma unroll
    for (int kt = 0; kt < 16; ++kt) {
#pragma unroll
      for (int n = 0; n < 4; ++n) {
        const int f = (nh4 * 4 + n) * 16 + kt;
        acc2[n] = __builtin_amdgcn_mfma_f32_16x16x32_bf16(ha[kt], bp[f * 64], acc2[n], 0, 0, 0);
      }
    }
  }
  const int rbase = b * 16 + (m ? NHALF_ROWS : 0);
#pragma unroll
  for (int n = 0; n < 4; ++n) {
    const int col = (nh4 * 4 + n) * 16 + lr;
    const float b2v = b2[col];
#pragma unroll
    for (int j = 0; j < 4; ++j) {
      const int rg = rbase + lk * 4 + j;
      out[rg * C_IN + col] = acc2[n][j] + b2v;
    }
  }
}

extern "C" void kernel_launch(void* const* d_in, const int* in_sizes, int n_in,
                              void* d_out, int out_size, void* d_ws, size_t ws_size,
                              hipStream_t stream) {
  const float* x  = (const float*)d_in[0];
  const float* ns = (const float*)d_in[1];
  const float* W1 = (const float*)d_in[2];
  const float* b1 = (const float*)d_in[3];
  const float* W2 = (const float*)d_in[4];
  const float* b2 = (const float*)d_in[5];
  float* out = (float*)d_out;

  short8* W1f = (short8*)d_ws;            // 256 frags * 64 lanes * 16B = 256 KB
  short8* W2f = W1f + 256 * 64;           // another 256 KB

  const int num_steps = in_sizes[1];      // 64
  // folded key = threefry_2x32(key=(0,42), counts=(0, last_step))
  uint32_t fk0, fk1;
  tf2x32(0u, 42u, 0u, (uint32_t)(num_steps - 1), fk0, fk1);

  const uint32_t nhalf = (uint32_t)(in_sizes[0] / 2);   // 1048576

  prep_kernel<<<128, 256, 0, stream>>>(W1, W2, W1f, W2f);
  fused_kernel<<<256, 512, 0, stream>>>(x, ns, b1, b2, W1f, W2f, out,
                                        fk0, fk1, num_steps - 1, nhalf);
}

// Round 4
// 90.189 us; speedup vs baseline: 1.0189x; 1.0189x over previous
//
#include <hip/hip_runtime.h>
#include <hip/hip_bf16.h>
#include <stdint.h>

typedef __attribute__((ext_vector_type(8))) short short8;
typedef __attribute__((ext_vector_type(4))) float f32x4;
typedef __attribute__((ext_vector_type(4))) unsigned short ushort4v;

#define C_IN 256
#define C_HID 512
#define NHALF_ROWS 4096

// ---------------- threefry-2x32 (matches jax.random) ----------------
__host__ __device__ __forceinline__ void tf2x32(uint32_t k0, uint32_t k1,
                                                uint32_t x0, uint32_t x1,
                                                uint32_t& o0, uint32_t& o1) {
  uint32_t ks2 = k0 ^ k1 ^ 0x1BD11BDAu;
#define TF_RND(r) { x0 += x1; x1 = (x1 << (r)) | (x1 >> (32 - (r))); x1 ^= x0; }
  x0 += k0; x1 += k1;
  TF_RND(13) TF_RND(15) TF_RND(26) TF_RND(6)
  x0 += k1; x1 += ks2 + 1u;
  TF_RND(17) TF_RND(29) TF_RND(16) TF_RND(24)
  x0 += ks2; x1 += k0 + 2u;
  TF_RND(13) TF_RND(15) TF_RND(26) TF_RND(6)
  x0 += k0; x1 += k1 + 3u;
  TF_RND(17) TF_RND(29) TF_RND(16) TF_RND(24)
  x0 += k1; x1 += ks2 + 4u;
  TF_RND(13) TF_RND(15) TF_RND(26) TF_RND(6)
  x0 += ks2; x1 += k0 + 5u;
#undef TF_RND
  o0 = x0; o1 = x1;
}

// bits -> N(0,1) exactly like jax.random.normal (uniform(-1+eps,1) -> sqrt2*erfinv)
__device__ __forceinline__ float bits_to_normal(uint32_t bits) {
  float u = __uint_as_float((bits >> 9) | 0x3f800000u) - 1.0f;  // [0,1)
  const float lo = -0.99999994f;                                 // nextafter(-1,0)
  float v = fmaxf(lo, fmaf(u, 2.0f, lo));                        // (hi-lo)==2.0f in fp32
  float w = -log1pf(-v * v);
  float p;
  if (w < 5.0f) {
    w -= 2.5f;
    p = 2.81022636e-08f;
    p = fmaf(p, w, 3.43273939e-07f);
    p = fmaf(p, w, -3.5233877e-06f);
    p = fmaf(p, w, -4.39150654e-06f);
    p = fmaf(p, w, 0.00021858087f);
    p = fmaf(p, w, -0.00125372503f);
    p = fmaf(p, w, -0.00417768164f);
    p = fmaf(p, w, 0.246640727f);
    p = fmaf(p, w, 1.50140941f);
  } else {
    w = sqrtf(w) - 3.0f;
    p = -0.000200214257f;
    p = fmaf(p, w, 0.000100950558f);
    p = fmaf(p, w, 0.00134934322f);
    p = fmaf(p, w, -0.00367342844f);
    p = fmaf(p, w, 0.00573950773f);
    p = fmaf(p, w, -0.0076224613f);
    p = fmaf(p, w, 0.00943887047f);
    p = fmaf(p, w, 1.00167406f);
    p = fmaf(p, w, 2.83297682f);
  }
  return 1.41421356237f * (p * v);
}

__device__ __forceinline__ unsigned short f2bf16(float f) {  // RNE, finite inputs
  uint32_t u = __float_as_uint(f);
  return (unsigned short)((u + 0x7fffu + ((u >> 16) & 1u)) >> 16);
}

// -------- prep: W1[256][512], W2[512][256] fp32 -> bf16 MFMA B-fragment layout --------
// frag(nt,kt): lane l, elem j holds W[k = kt*32 + (l>>4)*8 + j][n = nt*16 + (l&15)]
__global__ void __launch_bounds__(256) prep_kernel(const float* __restrict__ W1,
                                                   const float* __restrict__ W2,
                                                   short8* __restrict__ W1f,
                                                   short8* __restrict__ W2f) {
  const int t = threadIdx.x;
  const int l = t & 63;
  const int wv = t >> 6;           // 0..3
  const int lr = l & 15;
  const int lkb = (l >> 4) * 8;
  const int b = blockIdx.x;
  short8 v;
  if (b < 64) {                    // W1: 32 n-tiles x 8 k-tiles = 256 frags
    const int f = b * 4 + wv;
    const int nt = f >> 3, kt = f & 7;
    const int n = nt * 16 + lr;
    const int kb = kt * 32 + lkb;
#pragma unroll
    for (int j = 0; j < 8; ++j) v[j] = (short)f2bf16(W1[(kb + j) * 512 + n]);
    W1f[f * 64 + l] = v;
  } else {                         // W2: 16 n-tiles x 16 k-tiles = 256 frags
    const int f = (b - 64) * 4 + wv;
    const int nt = f >> 4, kt = f & 15;
    const int n = nt * 16 + lr;
    const int kb = kt * 32 + lkb;
#pragma unroll
    for (int j = 0; j < 8; ++j) v[j] = (short)f2bf16(W2[(kb + j) * 256 + n]);
    W2f[f * 64 + l] = v;
  }
}

// -------- fused: noise + x -> bf16 LDS -> GEMM1(relu,+b1) -> LDS -> GEMM2(+b2) -> out --------
// Each block: 16 "low" rows (b*16..) + 16 "high" rows (+4096) sharing threefry calls.
// Wave decomposition: 8 waves each own one N-octant and compute BOTH row halves
// (acc[n][m]) so every weight fragment is loaded exactly once per block (halves
// the L2 weight-fragment traffic vs the (m, nh4) wave-pair layout).
__global__ void __launch_bounds__(512) fused_kernel(
    const float* __restrict__ x, const float* __restrict__ ns,
    const float* __restrict__ b1, const float* __restrict__ b2,
    const short8* __restrict__ W1f, const short8* __restrict__ W2f,
    float* __restrict__ out, uint32_t fk0, uint32_t fk1, int nstep, uint32_t nhalf) {
  __shared__ __align__(16) unsigned char sA[32 * 512];    // 32 rows x 256 bf16 (swizzled)
  __shared__ __align__(16) unsigned char sH[32 * 1024];   // 32 rows x 512 bf16 (swizzled)

  const int t = threadIdx.x;
  const int b = blockIdx.x;
  const float nsv = ns[nstep];

  // ---- stage noisy A tile ----
  {
    const int rl = t >> 5;          // 0..15
    const int ln = t & 31;
    const int r_lo = b * 16 + rl;
    const int r_hi = r_lo + NHALF_ROWS;
    const int sw = (rl & 7) << 4;
#pragma unroll
    for (int i = 0; i < 2; ++i) {
      const int c = (i * 32 + ln) * 4;              // col, multiple of 4
      const float4 xl = *(const float4*)(x + r_lo * C_IN + c);
      const float4 xh = *(const float4*)(x + r_hi * C_IN + c);
      ushort4v vl, vh;
#pragma unroll
      for (int j = 0; j < 4; ++j) {
        uint32_t pidx = (uint32_t)(r_lo * C_IN + c + j);
        uint32_t o0, o1;
        tf2x32(fk0, fk1, pidx, pidx + nhalf, o0, o1);
        float nl = bits_to_normal(o0) * nsv;
        float nh = bits_to_normal(o1) * nsv;
        vl[j] = (unsigned short)f2bf16((&xl.x)[j] + nl);
        vh[j] = (unsigned short)f2bf16((&xh.x)[j] + nh);
      }
      const int byte_base = c * 2;                  // 8B aligned
      *(ushort4v*)(sA + rl * 512 + (byte_base ^ sw)) = vl;
      *(ushort4v*)(sA + (rl + 16) * 512 + (byte_base ^ sw)) = vh;
    }
  }
  __syncthreads();

  const int w = t >> 6;        // wave 0..7 = N-octant
  const int l = t & 63;
  const int lr = l & 15;
  const int lk = l >> 4;       // 0..3

  const int row0 = lr;              // m=0 A-row for this lane
  const int row1 = 16 + lr;         // m=1 A-row
  const int sw0 = (row0 & 7) << 4;
  const int sw1 = (row1 & 7) << 4;

  // ---- GEMM1: h[32x512] = relu(A @ W1 + b1); wave w covers cols [w*64, w*64+64) ----
  f32x4 acc[4][2];
#pragma unroll
  for (int n = 0; n < 4; ++n)
#pragma unroll
    for (int m = 0; m < 2; ++m) acc[n][m] = (f32x4){0.f, 0.f, 0.f, 0.f};
  {
    const short8* bp = W1f + l;
    const unsigned char* base0 = sA + row0 * 512;
    const unsigned char* base1 = sA + row1 * 512;
#pragma unroll
    for (int kt = 0; kt < 8; ++kt) {
      const int off = kt * 64 + lk * 16;
      short8 a0 = *(const short8*)(base0 + (off ^ sw0));
      short8 a1 = *(const short8*)(base1 + (off ^ sw1));
#pragma unroll
      for (int n = 0; n < 4; ++n) {
        const int f = (w * 4 + n) * 8 + kt;
        short8 bf = bp[f * 64];
        acc[n][0] = __builtin_amdgcn_mfma_f32_16x16x32_bf16(a0, bf, acc[n][0], 0, 0, 0);
        acc[n][1] = __builtin_amdgcn_mfma_f32_16x16x32_bf16(a1, bf, acc[n][1], 0, 0, 0);
      }
    }
  }
#pragma unroll
  for (int n = 0; n < 4; ++n) {
    const int col = (w * 4 + n) * 16 + lr;
    const float b1v = b1[col];
#pragma unroll
    for (int m = 0; m < 2; ++m)
#pragma unroll
      for (int j = 0; j < 4; ++j) {
        const int row = m * 16 + lk * 4 + j;
        float v = fmaxf(acc[n][m][j] + b1v, 0.f);
        *(unsigned short*)(sH + row * 1024 + ((col * 2) ^ ((row & 7) << 4))) = f2bf16(v);
      }
  }
  __syncthreads();

  // ---- GEMM2: y[32x256] = h @ W2 + b2; wave w covers cols [w*32, w*32+32) ----
  f32x4 acc2[2][2];
#pragma unroll
  for (int n = 0; n < 2; ++n)
#pragma unroll
    for (int m = 0; m < 2; ++m) acc2[n][m] = (f32x4){0.f, 0.f, 0.f, 0.f};
  {
    const short8* bp = W2f + l;
    const unsigned char* base0 = sH + row0 * 1024;
    const unsigned char* base1 = sH + row1 * 1024;
#pragma unroll
    for (int kt = 0; kt < 16; ++kt) {
      const int off = kt * 64 + lk * 16;
      short8 h0 = *(const short8*)(base0 + (off ^ sw0));
      short8 h1 = *(const short8*)(base1 + (off ^ sw1));
#pragma unroll
      for (int n = 0; n < 2; ++n) {
        const int f = (w * 2 + n) * 16 + kt;
        short8 bf = bp[f * 64];
        acc2[n][0] = __builtin_amdgcn_mfma_f32_16x16x32_bf16(h0, bf, acc2[n][0], 0, 0, 0);
        acc2[n][1] = __builtin_amdgcn_mfma_f32_16x16x32_bf16(h1, bf, acc2[n][1], 0, 0, 0);
      }
    }
  }
#pragma unroll
  for (int n = 0; n < 2; ++n) {
    const int col = (w * 2 + n) * 16 + lr;
    const float b2v = b2[col];
#pragma unroll
    for (int m = 0; m < 2; ++m) {
      const int rbase = b * 16 + (m ? NHALF_ROWS : 0);
#pragma unroll
      for (int j = 0; j < 4; ++j) {
        const int rg = rbase + lk * 4 + j;
        out[rg * C_IN + col] = acc2[n][m][j] + b2v;
      }
    }
  }
}

extern "C" void kernel_launch(void* const* d_in, const int* in_sizes, int n_in,
                              void* d_out, int out_size, void* d_ws, size_t ws_size,
                              hipStream_t stream) {
  const float* x  = (const float*)d_in[0];
  const float* ns = (const float*)d_in[1];
  const float* W1 = (const float*)d_in[2];
  const float* b1 = (const float*)d_in[3];
  const float* W2 = (const float*)d_in[4];
  const float* b2 = (const float*)d_in[5];
  float* out = (float*)d_out;

  short8* W1f = (short8*)d_ws;            // 256 frags * 64 lanes * 16B = 256 KB
  short8* W2f = W1f + 256 * 64;           // another 256 KB

  const int num_steps = in_sizes[1];      // 64
  // folded key = threefry_2x32(key=(0,42), counts=(0, last_step))
  uint32_t fk0, fk1;
  tf2x32(0u, 42u, 0u, (uint32_t)(num_steps - 1), fk0, fk1);

  const uint32_t nhalf = (uint32_t)(in_sizes[0] / 2);   // 1048576

  prep_kernel<<<128, 256, 0, stream>>>(W1, W2, W1f, W2f);
  fused_kernel<<<256, 512, 0, stream>>>(x, ns, b1, b2, W1f, W2f, out,
                                        fk0, fk1, num_steps - 1, nhalf);
}